// Round 9
// baseline (1399.188 us; speedup 1.0000x reference)
//
#include <hip/hip_runtime.h>
#include <hip/hip_fp16.h>
#include <hip/hip_bf16.h>

// Problem constants: B=16, S=1024, DIN=64, D=64
// out = [ z: 16*1024*64 fp32 | attn: 16*1024*1024 fp32 ]

typedef unsigned short u16;
typedef __attribute__((ext_vector_type(8))) short bhalf8;   // 8 bf16 - 16x16x32 A/B frag
typedef __attribute__((ext_vector_type(4))) short bhalf4;   // 4 bf16 - 16x16x16 A/B frag
typedef __attribute__((ext_vector_type(4))) float fx4;      // MFMA C/D frag

#if defined(__has_builtin)
#if __has_builtin(__builtin_amdgcn_mfma_f32_16x16x16bf16_1k)
#define HAS_MFMA16 1
#endif
#if __has_builtin(__builtin_amdgcn_fdot2)
#define HAS_FDOT2 1
#endif
#endif

// Raw barrier: LDS ordering only (lgkmcnt), never drains vmcnt.
__device__ __forceinline__ void bar_lds() {
  asm volatile("s_waitcnt lgkmcnt(0)" ::: "memory");
  __builtin_amdgcn_s_barrier();
}

__device__ __forceinline__ short b16(float f) {             // RNE
  __hip_bfloat16 h = __float2bfloat16(f);
  return *reinterpret_cast<short*>(&h);
}
__device__ __forceinline__ float bf2f(short s) {            // exact widen
  union { unsigned u; float f; } v; v.u = ((unsigned)(u16)s) << 16; return v.f;
}
__device__ __forceinline__ bhalf4 pk4(float4 a) {
  bhalf4 r; r[0] = b16(a.x); r[1] = b16(a.y); r[2] = b16(a.z); r[3] = b16(a.w); return r;
}
__device__ __forceinline__ bhalf8 pack8(float4 a, float4 b) {
  bhalf8 r;
  r[0] = b16(a.x); r[1] = b16(a.y); r[2] = b16(a.z); r[3] = b16(a.w);
  r[4] = b16(b.x); r[5] = b16(b.y); r[6] = b16(b.z); r[7] = b16(b.w);
  return r;
}

// dot of 8 fp16 pairs (two uint4 views), f32 accumulate
__device__ __forceinline__ float dot8(uint4 kv, uint4 qv, float acc) {
  const __half2* kp = (const __half2*)&kv;
  const __half2* qp = (const __half2*)&qv;
#ifdef HAS_FDOT2
  acc = __builtin_amdgcn_fdot2(kp[0], qp[0], acc, false);
  acc = __builtin_amdgcn_fdot2(kp[1], qp[1], acc, false);
  acc = __builtin_amdgcn_fdot2(kp[2], qp[2], acc, false);
  acc = __builtin_amdgcn_fdot2(kp[3], qp[3], acc, false);
#else
#pragma unroll
  for (int p = 0; p < 4; ++p) {
    float2 kf = __half22float2(kp[p]);
    float2 qf = __half22float2(qp[p]);
    acc = fmaf(kf.x, qf.x, acc);
    acc = fmaf(kf.y, qf.y, acc);
  }
#endif
  return acc;
}

// ---------------------------------------------------------------------------
// P1: q,k,v projections. grid 256, block 256. 64 rows/block, 4 threads/row.
// q -> bf16 (MFMA A-frags) + fp16 (dot); k -> fp16 (dot); v -> fp32.
__global__ __launch_bounds__(256) void k_proj(
    const float* __restrict__ x, const float* __restrict__ Wq,
    const float* __restrict__ Wk, const float* __restrict__ Wv,
    u16* __restrict__ qbf, __half* __restrict__ qh, __half* __restrict__ kh,
    float* __restrict__ vf)
{
  __shared__ float wl[3 * 4096];
  const int t = threadIdx.x;
  for (int c = t; c < 4096; c += 256) {
    wl[c] = Wq[c]; wl[4096 + c] = Wk[c]; wl[8192 + c] = Wv[c];
  }
  __syncthreads();
  const int row = blockIdx.x * 64 + (t >> 2);
  const int dbase = (t & 3) * 16;
  float xr[64];
  const float4* xp = (const float4*)(x + (size_t)row * 64);
#pragma unroll
  for (int c = 0; c < 16; ++c) {
    float4 v = xp[c];
    xr[4*c] = v.x; xr[4*c+1] = v.y; xr[4*c+2] = v.z; xr[4*c+3] = v.w;
  }
  float aq[16], ak[16], av[16];
#pragma unroll
  for (int m = 0; m < 16; ++m) { aq[m] = 0.f; ak[m] = 0.f; av[m] = 0.f; }
#pragma unroll
  for (int f = 0; f < 64; ++f) {
    const float xv = xr[f];
    const float* wq = wl + f * 64 + dbase;
#pragma unroll
    for (int m = 0; m < 16; ++m) {
      aq[m] = fmaf(xv, wq[m], aq[m]);
      ak[m] = fmaf(xv, wq[4096 + m], ak[m]);
      av[m] = fmaf(xv, wq[8192 + m], av[m]);
    }
  }
  union { u16 u[16]; uint4 q[2]; } pq;
  union { __half hf[16]; uint4 q[2]; } ph, pk2;
#pragma unroll
  for (int m = 0; m < 16; ++m) {
    pq.u[m]   = (u16)b16(aq[m]);
    ph.hf[m]  = __float2half(aq[m]);
    pk2.hf[m] = __float2half(ak[m]);
  }
  const size_t o = (size_t)row * 64 + dbase;
  *(uint4*)(qbf + o) = pq.q[0]; *(uint4*)(qbf + o + 8) = pq.q[1];
  *(uint4*)(qh + o)  = ph.q[0]; *(uint4*)(qh + o + 8)  = ph.q[1];
  *(uint4*)(kh + o)  = pk2.q[0]; *(uint4*)(kh + o + 8) = pk2.q[1];
  float4* vo = (float4*)(vf + o);
  vo[0] = make_float4(av[0], av[1], av[2], av[3]);
  vo[1] = make_float4(av[4], av[5], av[6], av[7]);
  vo[2] = make_float4(av[8], av[9], av[10], av[11]);
  vo[3] = make_float4(av[12], av[13], av[14], av[15]);
}

// ---------------------------------------------------------------------------
// P3: per-i core, j in two halves of 512, online softmax merge.
// QK^T computed IN-KERNEL via fp16 dot2 against L2-resident k (no qkw
// intermediate, no k_qk kernel): -64 MB demand traffic.
#define SLD2 516
#define PADJ 40
__global__ __launch_bounds__(256, 4) void k_core(
    const float* __restrict__ aK, const float* __restrict__ aV,
    const u16* __restrict__ qbf, const __half* __restrict__ qh,
    const __half* __restrict__ kh,
    float* __restrict__ attn_out, float* __restrict__ za)
{
  __shared__ __align__(16) float sl[16 * SLD2];   // 33,024 B scores (+ e-bf16 head)
  __shared__ __align__(16) u16 vt[64 * PADJ];     //  5,120 B aV^T tile
  __shared__ __align__(16) __half qsh[16 * 64];   //  2,048 B q rows (fp16, for dot)
  __shared__ float stats[64];  // [0:16) m1, [16:32) s1, [32:48) corr, [48:64) inv
  const int i = blockIdx.x;
  const int t = threadIdx.x, l = t & 63, w = t >> 6;
  const int lr = l & 15, lg = l >> 4;
  const int jj = l >> 2;          // phase-C: tile-local j
  const int cc = (l & 3) * 4;     // phase-C: d-chunk within wave's 16

  // stage q rows (fp16) for the dot: thread t -> b=t>>4, d0=(t&15)*4 (8 B)
  {
    const int bb = t >> 4, d0 = (t & 15) * 4;
    *(uint2*)(qsh + bb * 64 + d0) =
        *(const uint2*)(qh + ((size_t)bb * 1024 + i) * 64 + d0);
  }

#ifdef HAS_MFMA16
  // A-frags (16x16x16 layout): lane(lr,lg): m=b=lr, k = q*16 + lg*4
  const u16* qrow = qbf + (size_t)(lr * 1024 + i) * 64;
  bhalf4 aq0 = *(const bhalf4*)(qrow + 0  + lg * 4);
  bhalf4 aq1 = *(const bhalf4*)(qrow + 16 + lg * 4);
  bhalf4 aq2 = *(const bhalf4*)(qrow + 32 + lg * 4);
  bhalf4 aq3 = *(const bhalf4*)(qrow + 48 + lg * 4);
#else
  const u16* qp = qbf + (size_t)(lr * 1024 + i) * 64 + lg * 8;
  bhalf8 a0 = *(const bhalf8*)(qp);
  bhalf8 a1 = *(const bhalf8*)(qp + 32);
#endif

  fx4 zacc = {0.f, 0.f, 0.f, 0.f};   // D[m=b][n=d_local]: b=lg*4+r, d=w*16+lr
  bhalf4 e1b0[4], e1b1[4];           // half-0 raw e (rows w*4+rr; j=4l.. / 256+4l..)

  bar_lds();   // qsh visible to all waves

#pragma unroll
  for (int h = 0; h < 2; ++h) {
    // ---- phase A: sl = Q_i @ aK_half^T, 8 tiles, 2-deep pipeline
#ifdef HAS_MFMA16
    const float* baseA = aK + ((size_t)i * 1024 + h * 512 + lr) * 64 + lg * 4;
    auto ldA = [&](int tt, float4* c) {
      const float* p = baseA + (size_t)((w + tt * 4) * 16) * 64;
      c[0] = *(const float4*)(p);
      c[1] = *(const float4*)(p + 16);
      c[2] = *(const float4*)(p + 32);
      c[3] = *(const float4*)(p + 48);
    };
    auto doA = [&](int tt, const float4* c) {
      fx4 acc = {0.f, 0.f, 0.f, 0.f};
      acc = __builtin_amdgcn_mfma_f32_16x16x16bf16_1k(aq0, pk4(c[0]), acc, 0, 0, 0);
      acc = __builtin_amdgcn_mfma_f32_16x16x16bf16_1k(aq1, pk4(c[1]), acc, 0, 0, 0);
      acc = __builtin_amdgcn_mfma_f32_16x16x16bf16_1k(aq2, pk4(c[2]), acc, 0, 0, 0);
      acc = __builtin_amdgcn_mfma_f32_16x16x16bf16_1k(aq3, pk4(c[3]), acc, 0, 0, 0);
      const int j0 = (w + tt * 4) * 16;
#pragma unroll
      for (int r = 0; r < 4; ++r)          // C: col=lane&15 (j), row=(lane>>4)*4+r (b)
        sl[(lg * 4 + r) * SLD2 + j0 + lr] = acc[r];
    };
#else
    const float* baseA = aK + ((size_t)i * 1024 + h * 512 + lr) * 64 + lg * 8;
    auto ldA = [&](int tt, float4* c) {
      const float* p = baseA + (size_t)((w + tt * 4) * 16) * 64;
      c[0] = *(const float4*)(p);
      c[1] = *(const float4*)(p + 4);
      c[2] = *(const float4*)(p + 32);
      c[3] = *(const float4*)(p + 36);
    };
    auto doA = [&](int tt, const float4* c) {
      fx4 acc = {0.f, 0.f, 0.f, 0.f};
      acc = __builtin_amdgcn_mfma_f32_16x16x32_bf16(a0, pack8(c[0], c[1]), acc, 0, 0, 0);
      acc = __builtin_amdgcn_mfma_f32_16x16x32_bf16(a1, pack8(c[2], c[3]), acc, 0, 0, 0);
      const int j0 = (w + tt * 4) * 16;
#pragma unroll
      for (int r = 0; r < 4; ++r)
        sl[(lg * 4 + r) * SLD2 + j0 + lr] = acc[r];
    };
#endif
    float4 cA[4], cB[4];
    ldA(0, cA); ldA(1, cB);
#pragma unroll
    for (int tt = 0; tt < 8; tt += 2) {
      doA(tt, cA);     if (tt + 2 < 8) ldA(tt + 2, cA);
      doA(tt + 1, cB); if (tt + 3 < 8) ldA(tt + 3, cB);
    }

    // ---- QK dots (replaces the qkw round trip). Thread owns rows b=w*4+rr,
    // j = {4l..4l+3} and {256+4l..256+4l+3} (local to this half).
    // k rows come from L2 (k = 2 MB fp16, XCD-resident; lane reads 512 B
    // blocks of 4 consecutive rows -> L1-sector-friendly).
    float qd[4][8];
    {
      const int jl = 4 * l;
#pragma unroll
      for (int rr = 0; rr < 4; ++rr) {
        const int bb = w * 4 + rr;
        const __half* kb = kh + ((size_t)bb * 1024 + h * 512) * 64;
        float acc0[4] = {0.f, 0.f, 0.f, 0.f};
        float acc1[4] = {0.f, 0.f, 0.f, 0.f};
#pragma unroll
        for (int c = 0; c < 8; ++c) {
          uint4 q8 = *(const uint4*)(qsh + bb * 64 + c * 8);   // wave-uniform bcast
#pragma unroll
          for (int q4 = 0; q4 < 4; ++q4) {
            uint4 k8a = *(const uint4*)(kb + (size_t)(jl + q4) * 64 + c * 8);
            acc0[q4] = dot8(k8a, q8, acc0[q4]);
            uint4 k8b = *(const uint4*)(kb + (size_t)(256 + jl + q4) * 64 + c * 8);
            acc1[q4] = dot8(k8b, q8, acc1[q4]);
          }
        }
#pragma unroll
        for (int q4 = 0; q4 < 4; ++q4) { qd[rr][q4] = acc0[q4]; qd[rr][4 + q4] = acc1[q4]; }
      }
    }
    bar_lds();   // phase A sl writes visible; vmem stays in flight

    // ---- phase B: softmax rows w*4..w*4+3; lane owns j = {4l.., 256+4l..}
    if (h == 0) {
#pragma unroll
      for (int rr = 0; rr < 4; ++rr) {
        const int row = w * 4 + rr;
        float* rp = sl + row * SLD2;
        float4 x0 = *(const float4*)(rp + l * 4);
        float4 x1 = *(const float4*)(rp + 256 + l * 4);
        float v8[8] = {x0.x + qd[rr][0], x0.y + qd[rr][1], x0.z + qd[rr][2], x0.w + qd[rr][3],
                       x1.x + qd[rr][4], x1.y + qd[rr][5], x1.z + qd[rr][6], x1.w + qd[rr][7]};
        float mx = -3.0e30f;
#pragma unroll
        for (int c = 0; c < 8; ++c) mx = fmaxf(mx, v8[c]);
#pragma unroll
        for (int off = 32; off; off >>= 1) mx = fmaxf(mx, __shfl_xor(mx, off));
        float e8[8]; float sum = 0.f;
#pragma unroll
        for (int c = 0; c < 8; ++c) { e8[c] = __expf((v8[c] - mx) * 0.125f); sum += e8[c]; }
        bhalf4 eh0 = pk4(make_float4(e8[0], e8[1], e8[2], e8[3]));
        bhalf4 eh1 = pk4(make_float4(e8[4], e8[5], e8[6], e8[7]));
        *(bhalf4*)((u16*)rp + l * 4)       = eh0;            // e-bf16 row head (PV A-frag)
        *(bhalf4*)((u16*)rp + 256 + l * 4) = eh1;
        e1b0[rr] = eh0; e1b1[rr] = eh1;                      // keep for final attn write
#pragma unroll
        for (int off = 32; off; off >>= 1) sum += __shfl_xor(sum, off);
        if (l == 0) { stats[row] = mx; stats[16 + row] = sum; }
      }
    } else {
#pragma unroll
      for (int rr = 0; rr < 4; ++rr) {
        const int row = w * 4 + rr;
        float* rp = sl + row * SLD2;
        float4 x0 = *(const float4*)(rp + l * 4);
        float4 x1 = *(const float4*)(rp + 256 + l * 4);
        float v8[8] = {x0.x + qd[rr][0], x0.y + qd[rr][1], x0.z + qd[rr][2], x0.w + qd[rr][3],
                       x1.x + qd[rr][4], x1.y + qd[rr][5], x1.z + qd[rr][6], x1.w + qd[rr][7]};
        float mx = -3.0e30f;
#pragma unroll
        for (int c = 0; c < 8; ++c) mx = fmaxf(mx, v8[c]);
#pragma unroll
        for (int off = 32; off; off >>= 1) mx = fmaxf(mx, __shfl_xor(mx, off));
        const float m1 = stats[row];
        const float m  = fmaxf(m1, mx);
        const float corr = __expf((m1 - m) * 0.125f);
        float e8[8]; float sum = 0.f;
#pragma unroll
        for (int c = 0; c < 8; ++c) { e8[c] = __expf((v8[c] - m) * 0.125f); sum += e8[c]; }
        bhalf4 eh0 = pk4(make_float4(e8[0], e8[1], e8[2], e8[3]));
        bhalf4 eh1 = pk4(make_float4(e8[4], e8[5], e8[6], e8[7]));
        *(bhalf4*)((u16*)rp + l * 4)       = eh0;            // raw e2 for PV
        *(bhalf4*)((u16*)rp + 256 + l * 4) = eh1;
#pragma unroll
        for (int off = 32; off; off >>= 1) sum += __shfl_xor(sum, off);
        const float inv = 1.0f / (stats[16 + row] * corr + sum);
        float* ao1 = attn_out + ((size_t)row * 1024 + i) * 1024 + 512;
        *(float4*)(ao1 + l * 4)       = make_float4(e8[0]*inv, e8[1]*inv, e8[2]*inv, e8[3]*inv);
        *(float4*)(ao1 + 256 + l * 4) = make_float4(e8[4]*inv, e8[5]*inv, e8[6]*inv, e8[7]*inv);
        const float f = corr * inv;
        float* ao0 = attn_out + ((size_t)row * 1024 + i) * 1024;
        *(float4*)(ao0 + l * 4)       = make_float4(bf2f(e1b0[rr][0])*f, bf2f(e1b0[rr][1])*f,
                                                    bf2f(e1b0[rr][2])*f, bf2f(e1b0[rr][3])*f);
        *(float4*)(ao0 + 256 + l * 4) = make_float4(bf2f(e1b1[rr][0])*f, bf2f(e1b1[rr][1])*f,
                                                    bf2f(e1b1[rr][2])*f, bf2f(e1b1[rr][3])*f);
        if (l == 0) { stats[32 + row] = corr; stats[48 + row] = inv; }
      }
    }
    bar_lds();   // e-heads + stats visible

    // ---- phase C: PV (barrier-free, per-wave-private vt), 4-deep rotation.
    if (h == 1) {
#pragma unroll
      for (int r = 0; r < 4; ++r) zacc[r] *= stats[32 + lg * 4 + r];   // corr
    }
    const float* avbase = aV + ((size_t)i * 1024 + h * 512) * 64 + w * 16 + cc;
    auto ldC = [&](int it, float4& pa, float4& pb) {
      const float* nb = avbase + (size_t)(it * 32) * 64;
      pa = *(const float4*)(nb + (size_t)jj * 64);
      pb = *(const float4*)(nb + (size_t)(jj + 16) * 64);
    };
    u16* vtw = vt + (size_t)(w * 16 + cc) * PADJ + jj;
    const u16* vtr = vt + (size_t)(w * 16 + lr) * PADJ + lg * 8;
    const u16* slr = (const u16*)(sl + (size_t)lr * SLD2);
    auto doC = [&](int it, float4 ca, float4 cb) {
      vtw[0 * PADJ]      = (u16)b16(ca.x);
      vtw[1 * PADJ]      = (u16)b16(ca.y);
      vtw[2 * PADJ]      = (u16)b16(ca.z);
      vtw[3 * PADJ]      = (u16)b16(ca.w);
      vtw[0 * PADJ + 16] = (u16)b16(cb.x);
      vtw[1 * PADJ + 16] = (u16)b16(cb.y);
      vtw[2 * PADJ + 16] = (u16)b16(cb.z);
      vtw[3 * PADJ + 16] = (u16)b16(cb.w);
      // within-wave LDS write->read (in-order DS pipe; compiler orders may-alias)
      bhalf8 ea = *(const bhalf8*)(slr + it * 32 + lg * 8);
      bhalf8 bv = *(const bhalf8*)(vtr);
      zacc = __builtin_amdgcn_mfma_f32_16x16x32_bf16(ea, bv, zacc, 0, 0, 0);
    };
    float4 p0a, p0b, p1a, p1b, p2a, p2b, p3a, p3b;
    ldC(0, p0a, p0b); ldC(1, p1a, p1b); ldC(2, p2a, p2b); ldC(3, p3a, p3b);
#pragma unroll
    for (int it = 0; it < 16; it += 4) {
      doC(it + 0, p0a, p0b); if (it + 4 < 16) ldC(it + 4, p0a, p0b);
      doC(it + 1, p1a, p1b); if (it + 5 < 16) ldC(it + 5, p1a, p1b);
      doC(it + 2, p2a, p2b); if (it + 6 < 16) ldC(it + 6, p2a, p2b);
      doC(it + 3, p3a, p3b); if (it + 7 < 16) ldC(it + 7, p3a, p3b);
    }
    bar_lds();   // protect sl/vt until all waves' PV done
  }

  // ---- za directly from accumulator: b = lg*4+r, d = w*16+lr
#pragma unroll
  for (int r = 0; r < 4; ++r) {
    const int b = lg * 4 + r;
    za[((size_t)i * 16 + b) * 64 + w * 16 + lr] = zacc[r] * stats[48 + b];
  }
}

// ---------------------------------------------------------------------------
// P4: z[b,i,d] = attn[b,i,:] @ v[b,:,d] + z_a[i,b,d].
// grid 1024 (b x 16-row i-tile). Dense attn A-frags via 16x16x16; per-wave-
// private v^T staging (no barriers at all in this kernel).
__global__ __launch_bounds__(256) void k_zv(
    const float* __restrict__ attn, const float* __restrict__ vf,
    const float* __restrict__ za, float* __restrict__ zout)
{
  __shared__ __align__(16) u16 vt[64 * PADJ];
  const int t = threadIdx.x, l = t & 63, w = t >> 6;
  const int b = blockIdx.x & 15, it16 = blockIdx.x >> 4;
  const int lr = l & 15, lg = l >> 4;
  const int i0 = it16 * 16;
  const int jj = l >> 2;
  const int cc = (l & 3) * 4;
  const float* vbase = vf + (size_t)b * 65536 + w * 16 + cc;
  float zr[4];
#pragma unroll
  for (int r = 0; r < 4; ++r)
    zr[r] = za[((size_t)(i0 + lg * 4 + r) * 16 + b) * 64 + w * 16 + lr];
  fx4 acc = {0.f, 0.f, 0.f, 0.f};
  u16* vtw = vt + (size_t)(w * 16 + cc) * PADJ + jj;
  auto ldV = [&](int jt, float4& pa, float4& pb) {
    const float* nb = vbase + (size_t)(jt * 32) * 64;
    pa = *(const float4*)(nb + (size_t)jj * 64);
    pb = *(const float4*)(nb + (size_t)(jj + 16) * 64);
  };
#ifdef HAS_MFMA16
  const float* abase = attn + ((size_t)(b * 1024 + i0 + lr)) * 1024 + lg * 4;
  auto ldAt = [&](int jt, float4& t0, float4& t1) {
    const float* p = abase + jt * 32;
    t0 = *(const float4*)(p);
    t1 = *(const float4*)(p + 16);
  };
#else
  const float* abase = attn + ((size_t)(b * 1024 + i0 + lr)) * 1024 + lg * 8;
  auto ldAt = [&](int jt, float4& t0, float4& t1) {
    const float* p = abase + jt * 32;
    t0 = *(const float4*)(p);
    t1 = *(const float4*)(p + 4);
  };
#endif
  auto doT = [&](float4 va, float4 vb, float4 t0, float4 t1) {
    vtw[0 * PADJ]      = (u16)b16(va.x);
    vtw[1 * PADJ]      = (u16)b16(va.y);
    vtw[2 * PADJ]      = (u16)b16(va.z);
    vtw[3 * PADJ]      = (u16)b16(va.w);
    vtw[0 * PADJ + 16] = (u16)b16(vb.x);
    vtw[1 * PADJ + 16] = (u16)b16(vb.y);
    vtw[2 * PADJ + 16] = (u16)b16(vb.z);
    vtw[3 * PADJ + 16] = (u16)b16(vb.w);
#ifdef HAS_MFMA16
    bhalf4 bv0 = *(const bhalf4*)(vt + (size_t)(w * 16 + lr) * PADJ + lg * 4);
    bhalf4 bv1 = *(const bhalf4*)(vt + (size_t)(w * 16 + lr) * PADJ + 16 + lg * 4);
    acc = __builtin_amdgcn_mfma_f32_16x16x16bf16_1k(pk4(t0), bv0, acc, 0, 0, 0);
    acc = __builtin_amdgcn_mfma_f32_16x16x16bf16_1k(pk4(t1), bv1, acc, 0, 0, 0);
#else
    bhalf8 af = pack8(t0, t1);
    bhalf8 bv = *(const bhalf8*)(vt + (size_t)(w * 16 + lr) * PADJ + lg * 8);
    acc = __builtin_amdgcn_mfma_f32_16x16x32_bf16(af, bv, acc, 0, 0, 0);
#endif
  };
  float4 v0a, v0b, v1a, v1b, v2a, v2b, v3a, v3b;
  float4 a0_, a1_, b0_, b1_, c0_, c1_, d0_, d1_;
  ldV(0, v0a, v0b); ldAt(0, a0_, a1_);
  ldV(1, v1a, v1b); ldAt(1, b0_, b1_);
  ldV(2, v2a, v2b); ldAt(2, c0_, c1_);
  ldV(3, v3a, v3b); ldAt(3, d0_, d1_);
#pragma unroll
  for (int jt = 0; jt < 32; jt += 4) {
    doT(v0a, v0b, a0_, a1_); if (jt + 4 < 32) { ldV(jt + 4, v0a, v0b); ldAt(jt + 4, a0_, a1_); }
    doT(v1a, v1b, b0_, b1_); if (jt + 5 < 32) { ldV(jt + 5, v1a, v1b); ldAt(jt + 5, b0_, b1_); }
    doT(v2a, v2b, c0_, c1_); if (jt + 6 < 32) { ldV(jt + 6, v2a, v2b); ldAt(jt + 6, c0_, c1_); }
    doT(v3a, v3b, d0_, d1_); if (jt + 7 < 32) { ldV(jt + 7, v3a, v3b); ldAt(jt + 7, d0_, d1_); }
  }
#pragma unroll
  for (int r = 0; r < 4; ++r)
    zout[((size_t)b * 1024 + i0 + lg * 4 + r) * 64 + w * 16 + lr] = acc[r] + zr[r];
}

// ---------------------------------------------------------------------------
extern "C" void kernel_launch(void* const* d_in, const int* in_sizes, int n_in,
                              void* d_out, int out_size, void* d_ws, size_t ws_size,
                              hipStream_t stream)
{
  const float* x  = (const float*)d_in[0];
  const float* Wq = (const float*)d_in[1];
  const float* Wk = (const float*)d_in[2];
  const float* Wv = (const float*)d_in[3];
  const float* aK = (const float*)d_in[4];
  const float* aV = (const float*)d_in[5];
  float* zout = (float*)d_out;
  float* attn_out = zout + (size_t)16 * 1024 * 64;   // attn after z

  char* ws = (char*)d_ws;                 // layout (14 MB used):
  u16*    qbf = (u16*)(ws);                               //  0.. 2 MB q bf16 (MFMA)
  __half* qh  = (__half*)(ws + (size_t)2  * 1024 * 1024); //  2.. 4 MB q fp16 (dot)
  __half* kh  = (__half*)(ws + (size_t)4  * 1024 * 1024); //  4.. 6 MB k fp16 (dot)
  float*  vf  = (float*)(ws + (size_t)6  * 1024 * 1024);  //  6..10 MB v fp32
  float*  za  = (float*)(ws + (size_t)10 * 1024 * 1024);  // 10..14 MB z_a [i][b][d]

  hipLaunchKernelGGL(k_proj, dim3(256),  dim3(256), 0, stream, x, Wq, Wk, Wv, qbf, qh, kh, vf);
  hipLaunchKernelGGL(k_core, dim3(1024), dim3(256), 0, stream, aK, aV, qbf, qh, kh, attn_out, za);
  hipLaunchKernelGGL(k_zv,   dim3(1024), dim3(256), 0, stream, attn_out, vf, za, zout);
}

// Round 11
// 206.610 us; speedup vs baseline: 6.7721x; 6.7721x over previous
//
#include <hip/hip_runtime.h>
#include <hip/hip_fp16.h>
#include <hip/hip_bf16.h>

// Problem constants: B=16, S=1024, DIN=64, D=64
// out = [ z: 16*1024*64 fp32 | attn: 16*1024*1024 fp32 ]
// Structure = Round-5 best (206.7 us) + NON-TEMPORAL loads on the two
// read-once 256 MB streams (aK, aV): no-allocate keeps L3 for the reused
// ~110 MB (qkw, attn->k_zv, k/q/v, za) and removes L3 fill/evict traffic.

typedef unsigned short u16;
typedef __attribute__((ext_vector_type(8))) short bhalf8;   // 8 bf16 (4 VGPRs) - MFMA A/B frag
typedef __attribute__((ext_vector_type(4))) float fx4;      // MFMA C/D frag / NT load vehicle

__device__ __forceinline__ short b16(float f) {             // RNE; pairs fuse to v_cvt_pk_bf16_f32
  __hip_bfloat16 h = __float2bfloat16(f);
  return *reinterpret_cast<short*>(&h);
}
__device__ __forceinline__ float bf2f(short s) {            // exact widen
  union { unsigned u; float f; } v; v.u = ((unsigned)(u16)s) << 16; return v.f;
}

__device__ __forceinline__ bhalf8 pack8(float4 a, float4 b) {
  bhalf8 r;
  r[0] = b16(a.x); r[1] = b16(a.y); r[2] = b16(a.z); r[3] = b16(a.w);
  r[4] = b16(b.x); r[5] = b16(b.y); r[6] = b16(b.z); r[7] = b16(b.w);
  return r;
}

// streaming (no-allocate) float4 load — via ext_vector (builtin requires
// scalar/ext-vector pointee; HIP_vector_type struct is rejected)
__device__ __forceinline__ float4 ldnt(const float* p) {
  fx4 v = __builtin_nontemporal_load((const fx4*)p);
  return make_float4(v[0], v[1], v[2], v[3]);
}

// ---------------------------------------------------------------------------
// P1: q,k,v projections. grid 256, block 256. 64 rows/block, 4 threads/row.
__global__ __launch_bounds__(256) void k_proj(
    const float* __restrict__ x, const float* __restrict__ Wq,
    const float* __restrict__ Wk, const float* __restrict__ Wv,
    u16* __restrict__ qbf, u16* __restrict__ kbf, float* __restrict__ vf)
{
  __shared__ float wl[3 * 4096];
  const int t = threadIdx.x;
  for (int c = t; c < 4096; c += 256) {
    wl[c] = Wq[c]; wl[4096 + c] = Wk[c]; wl[8192 + c] = Wv[c];
  }
  __syncthreads();
  const int row = blockIdx.x * 64 + (t >> 2);
  const int dbase = (t & 3) * 16;
  float xr[64];
  const float4* xp = (const float4*)(x + (size_t)row * 64);
#pragma unroll
  for (int c = 0; c < 16; ++c) {
    float4 v = xp[c];
    xr[4*c] = v.x; xr[4*c+1] = v.y; xr[4*c+2] = v.z; xr[4*c+3] = v.w;
  }
  float aq[16], ak[16], av[16];
#pragma unroll
  for (int m = 0; m < 16; ++m) { aq[m] = 0.f; ak[m] = 0.f; av[m] = 0.f; }
#pragma unroll
  for (int f = 0; f < 64; ++f) {
    const float xv = xr[f];
    const float* wq = wl + f * 64 + dbase;
#pragma unroll
    for (int m = 0; m < 16; ++m) {
      aq[m] = fmaf(xv, wq[m], aq[m]);
      ak[m] = fmaf(xv, wq[4096 + m], ak[m]);
      av[m] = fmaf(xv, wq[8192 + m], av[m]);
    }
  }
  union { u16 u[16]; uint4 q[2]; } pq, pk;
#pragma unroll
  for (int m = 0; m < 16; ++m) { pq.u[m] = (u16)b16(aq[m]); pk.u[m] = (u16)b16(ak[m]); }
  const size_t o = (size_t)row * 64 + dbase;
  *(uint4*)(qbf + o) = pq.q[0]; *(uint4*)(qbf + o + 8) = pq.q[1];
  *(uint4*)(kbf + o) = pk.q[0]; *(uint4*)(kbf + o + 8) = pk.q[1];
  float4* vo = (float4*)(vf + o);
  vo[0] = make_float4(av[0], av[1], av[2], av[3]);
  vo[1] = make_float4(av[4], av[5], av[6], av[7]);
  vo[2] = make_float4(av[8], av[9], av[10], av[11]);
  vo[3] = make_float4(av[12], av[13], av[14], av[15]);
}

// ---------------------------------------------------------------------------
// P2: QK[b,i,j] = q[b,i].k[b,j] (unscaled), stored fp16 layout [i][b][j].
// 4-deep prefetch rotation on the K-tile stream.
__global__ __launch_bounds__(256) void k_qk(
    const u16* __restrict__ qbf, const u16* __restrict__ kbf, __half* __restrict__ qkw)
{
  const int t = threadIdx.x, l = t & 63, w = t >> 6;
  const int bq = blockIdx.x & 15, it = blockIdx.x >> 4;
  const int lr = l & 15, lg = l >> 4;
  const int i0 = it * 64 + w * 16;
  const u16* qp = qbf + (size_t)(bq * 1024 + i0 + lr) * 64 + lg * 8;
  bhalf8 a0 = *(const bhalf8*)(qp);
  bhalf8 a1 = *(const bhalf8*)(qp + 32);
  auto ldK = [&](int jt, bhalf8& b0, bhalf8& b1) {
    const u16* kp = kbf + (size_t)(bq * 1024 + jt * 16 + lr) * 64 + lg * 8;
    b0 = *(const bhalf8*)(kp);
    b1 = *(const bhalf8*)(kp + 32);
  };
  auto doK = [&](int jt, bhalf8 b0, bhalf8 b1) {
    fx4 acc = {0.f, 0.f, 0.f, 0.f};
    acc = __builtin_amdgcn_mfma_f32_16x16x32_bf16(a0, b0, acc, 0, 0, 0);
    acc = __builtin_amdgcn_mfma_f32_16x16x32_bf16(a1, b1, acc, 0, 0, 0);
#pragma unroll
    for (int r = 0; r < 4; ++r) {
      const int i = i0 + lg * 4 + r;
      qkw[((size_t)i * 16 + bq) * 1024 + jt * 16 + lr] = __float2half(acc[r]);
    }
  };
  bhalf8 k0a, k0b, k1a, k1b, k2a, k2b, k3a, k3b;
  ldK(0, k0a, k0b); ldK(1, k1a, k1b); ldK(2, k2a, k2b); ldK(3, k3a, k3b);
#pragma unroll
  for (int jt = 0; jt < 64; jt += 4) {
    doK(jt + 0, k0a, k0b); if (jt + 4 < 64) ldK(jt + 4, k0a, k0b);
    doK(jt + 1, k1a, k1b); if (jt + 5 < 64) ldK(jt + 5, k1a, k1b);
    doK(jt + 2, k2a, k2b); if (jt + 6 < 64) ldK(jt + 6, k2a, k2b);
    doK(jt + 3, k3a, k3b); if (jt + 7 < 64) ldK(jt + 7, k3a, k3b);
  }
}

// ---------------------------------------------------------------------------
// P3: per-i core, j in two halves of 512, online softmax merge.
// Phase A 2-deep pipeline (NT aK loads), qkw prefetched under A, half-0 e in
// regs (no fixup), phase C 4-deep rotation (NT aV loads).
#define SLD2 516
#define PADJ 40
__global__ __launch_bounds__(256, 4) void k_core(
    const float* __restrict__ aK, const float* __restrict__ aV,
    const u16* __restrict__ qbf, const __half* __restrict__ qkw,
    float* __restrict__ attn_out, float* __restrict__ za)
{
  __shared__ __align__(16) float sl[16 * SLD2];   // 33,024 B
  __shared__ __align__(16) u16 vt[64 * PADJ];     //  5,120 B
  __shared__ float stats[64];  // [0:16) m1, [16:32) s1, [32:48) corr, [48:64) inv
  const int i = blockIdx.x;
  const int t = threadIdx.x, l = t & 63, w = t >> 6;
  const int lr = l & 15, lg = l >> 4;
  const int jj = l >> 2;          // phase-C: tile-local j
  const int cc = (l & 3) * 4;     // phase-C: d-chunk within wave's 16

  // A-frags: Q rows b=lr at position i  (A[m=b][k=d])
  const u16* qp = qbf + (size_t)(lr * 1024 + i) * 64 + lg * 8;
  bhalf8 a0 = *(const bhalf8*)(qp);
  bhalf8 a1 = *(const bhalf8*)(qp + 32);

  fx4 zacc = {0.f, 0.f, 0.f, 0.f};   // D[m=b][n=d_local]: b=lg*4+r, d=w*16+lr
  bhalf8 e1b[4];                     // half-0 raw e (rows w*4+rr, j=l*8..+7)

#pragma unroll
  for (int h = 0; h < 2; ++h) {
    // ---- prefetch qkw rows for phase B (in flight across phase A; cached —
    // qkw is the write->read reuse L3 should keep)
    uint4 qv[4];
#pragma unroll
    for (int rr = 0; rr < 4; ++rr)
      qv[rr] = *(const uint4*)(qkw + ((size_t)i * 16 + w * 4 + rr) * 1024 + h * 512 + l * 8);

    // ---- phase A: sl = Q_i @ aK_half^T, 8 tiles, 2-deep pipeline, NT loads
    const float* base = aK + ((size_t)i * 1024 + h * 512 + lr) * 64 + lg * 8;
    auto ldA = [&](int tt, float4* c) {
      const float* p = base + (size_t)((w + tt * 4) * 16) * 64;
      c[0] = ldnt(p);
      c[1] = ldnt(p + 4);
      c[2] = ldnt(p + 32);
      c[3] = ldnt(p + 36);
    };
    auto doA = [&](int tt, const float4* c) {
      fx4 acc = {0.f, 0.f, 0.f, 0.f};
      acc = __builtin_amdgcn_mfma_f32_16x16x32_bf16(a0, pack8(c[0], c[1]), acc, 0, 0, 0);
      acc = __builtin_amdgcn_mfma_f32_16x16x32_bf16(a1, pack8(c[2], c[3]), acc, 0, 0, 0);
      const int j0 = (w + tt * 4) * 16;
#pragma unroll
      for (int r = 0; r < 4; ++r)          // C: col=lane&15 (j), row=(lane>>4)*4+r (b)
        sl[(lg * 4 + r) * SLD2 + j0 + lr] = acc[r];
    };
    float4 cA[4], cB[4];
    ldA(0, cA); ldA(1, cB);
#pragma unroll
    for (int tt = 0; tt < 8; tt += 2) {
      doA(tt, cA);     if (tt + 2 < 8) ldA(tt + 2, cA);
      doA(tt + 1, cB); if (tt + 3 < 8) ldA(tt + 3, cB);
    }
    __syncthreads();

    // ---- phase B: softmax rows w*4..w*4+3; lane covers j = l*8..l*8+7
    if (h == 0) {
#pragma unroll
      for (int rr = 0; rr < 4; ++rr) {
        const int row = w * 4 + rr;
        float* rp = sl + row * SLD2;
        const __half2* hh = (const __half2*)&qv[rr];
        float2 f0 = __half22float2(hh[0]);
        float2 f1 = __half22float2(hh[1]);
        float2 f2 = __half22float2(hh[2]);
        float2 f3 = __half22float2(hh[3]);
        float4 x0 = *(const float4*)(rp + l * 8);
        float4 x1 = *(const float4*)(rp + l * 8 + 4);
        float v8[8] = {x0.x + f0.x, x0.y + f0.y, x0.z + f1.x, x0.w + f1.y,
                       x1.x + f2.x, x1.y + f2.y, x1.z + f3.x, x1.w + f3.y};
        float mx = -3.0e30f;
#pragma unroll
        for (int c = 0; c < 8; ++c) mx = fmaxf(mx, v8[c]);
#pragma unroll
        for (int off = 32; off; off >>= 1) mx = fmaxf(mx, __shfl_xor(mx, off));
        float e8[8]; float sum = 0.f;
#pragma unroll
        for (int c = 0; c < 8; ++c) { e8[c] = __expf((v8[c] - mx) * 0.125f); sum += e8[c]; }
        bhalf8 eb;
#pragma unroll
        for (int c = 0; c < 8; ++c) eb[c] = b16(e8[c]);
        *(bhalf8*)((u16*)rp + l * 8) = eb;                  // e-bf16 row head (PV A-frag)
        e1b[rr] = eb;                                       // keep for final attn write
#pragma unroll
        for (int off = 32; off; off >>= 1) sum += __shfl_xor(sum, off);
        if (l == 0) { stats[row] = mx; stats[16 + row] = sum; }
      }
    } else {
#pragma unroll
      for (int rr = 0; rr < 4; ++rr) {
        const int row = w * 4 + rr;
        float* rp = sl + row * SLD2;
        const __half2* hh = (const __half2*)&qv[rr];
        float2 f0 = __half22float2(hh[0]);
        float2 f1 = __half22float2(hh[1]);
        float2 f2 = __half22float2(hh[2]);
        float2 f3 = __half22float2(hh[3]);
        float4 x0 = *(const float4*)(rp + l * 8);
        float4 x1 = *(const float4*)(rp + l * 8 + 4);
        float v8[8] = {x0.x + f0.x, x0.y + f0.y, x0.z + f1.x, x0.w + f1.y,
                       x1.x + f2.x, x1.y + f2.y, x1.z + f3.x, x1.w + f3.y};
        float mx = -3.0e30f;
#pragma unroll
        for (int c = 0; c < 8; ++c) mx = fmaxf(mx, v8[c]);
#pragma unroll
        for (int off = 32; off; off >>= 1) mx = fmaxf(mx, __shfl_xor(mx, off));
        const float m1 = stats[row];
        const float m  = fmaxf(m1, mx);
        const float corr = __expf((m1 - m) * 0.125f);
        float e8[8]; float sum = 0.f;
#pragma unroll
        for (int c = 0; c < 8; ++c) { e8[c] = __expf((v8[c] - m) * 0.125f); sum += e8[c]; }
        bhalf8 eb;
#pragma unroll
        for (int c = 0; c < 8; ++c) eb[c] = b16(e8[c]);
        *(bhalf8*)((u16*)rp + l * 8) = eb;                  // raw e2 for PV
#pragma unroll
        for (int off = 32; off; off >>= 1) sum += __shfl_xor(sum, off);
        const float inv = 1.0f / (stats[16 + row] * corr + sum);
        // final attn half-1
        float* ao1 = attn_out + ((size_t)row * 1024 + i) * 1024 + 512;
        *(float4*)(ao1 + l * 8)     = make_float4(e8[0]*inv, e8[1]*inv, e8[2]*inv, e8[3]*inv);
        *(float4*)(ao1 + l * 8 + 4) = make_float4(e8[4]*inv, e8[5]*inv, e8[6]*inv, e8[7]*inv);
        // final attn half-0 from register-held bf16 e1 (no re-read, no fixup)
        const float f = corr * inv;
        float* ao0 = attn_out + ((size_t)row * 1024 + i) * 1024;
        *(float4*)(ao0 + l * 8)     = make_float4(bf2f(e1b[rr][0])*f, bf2f(e1b[rr][1])*f,
                                                  bf2f(e1b[rr][2])*f, bf2f(e1b[rr][3])*f);
        *(float4*)(ao0 + l * 8 + 4) = make_float4(bf2f(e1b[rr][4])*f, bf2f(e1b[rr][5])*f,
                                                  bf2f(e1b[rr][6])*f, bf2f(e1b[rr][7])*f);
        if (l == 0) { stats[32 + row] = corr; stats[48 + row] = inv; }
      }
    }
    __syncthreads();

    // ---- phase C: PV (barrier-free, per-wave-private vt), 4-deep rotation,
    // NT aV loads (read-once stream).
    if (h == 1) {
#pragma unroll
      for (int r = 0; r < 4; ++r) zacc[r] *= stats[32 + lg * 4 + r];   // corr
    }
    const float* avbase = aV + ((size_t)i * 1024 + h * 512) * 64 + w * 16 + cc;
    u16* vtw = vt + (size_t)(w * 16 + cc) * PADJ + jj;
    const u16* vtr = vt + (size_t)(w * 16 + lr) * PADJ + lg * 8;
    const u16* slr = (const u16*)(sl + (size_t)lr * SLD2);
    auto ldC = [&](int it, float4& pa, float4& pb) {
      const float* nb = avbase + (size_t)(it * 32) * 64;
      pa = ldnt(nb + (size_t)jj * 64);
      pb = ldnt(nb + (size_t)(jj + 16) * 64);
    };
    auto doC = [&](int it, float4 ca, float4 cb) {
      vtw[0 * PADJ]      = (u16)b16(ca.x);
      vtw[1 * PADJ]      = (u16)b16(ca.y);
      vtw[2 * PADJ]      = (u16)b16(ca.z);
      vtw[3 * PADJ]      = (u16)b16(ca.w);
      vtw[0 * PADJ + 16] = (u16)b16(cb.x);
      vtw[1 * PADJ + 16] = (u16)b16(cb.y);
      vtw[2 * PADJ + 16] = (u16)b16(cb.z);
      vtw[3 * PADJ + 16] = (u16)b16(cb.w);
      // within-wave LDS write->read (in-order DS pipe; compiler orders may-alias)
      bhalf8 ea = *(const bhalf8*)(slr + it * 32 + lg * 8);
      bhalf8 bv = *(const bhalf8*)(vtr);
      zacc = __builtin_amdgcn_mfma_f32_16x16x32_bf16(ea, bv, zacc, 0, 0, 0);
    };
    float4 p0a, p0b, p1a, p1b, p2a, p2b, p3a, p3b;
    ldC(0, p0a, p0b); ldC(1, p1a, p1b); ldC(2, p2a, p2b); ldC(3, p3a, p3b);
#pragma unroll
    for (int it = 0; it < 16; it += 4) {
      doC(it + 0, p0a, p0b); if (it + 4 < 16) ldC(it + 4, p0a, p0b);
      doC(it + 1, p1a, p1b); if (it + 5 < 16) ldC(it + 5, p1a, p1b);
      doC(it + 2, p2a, p2b); if (it + 6 < 16) ldC(it + 6, p2a, p2b);
      doC(it + 3, p3a, p3b); if (it + 7 < 16) ldC(it + 7, p3a, p3b);
    }
    __syncthreads();   // protect sl/vt until all waves' PV done
  }

  // ---- za directly from accumulator: b = lg*4+r, d = w*16+lr
#pragma unroll
  for (int r = 0; r < 4; ++r) {
    const int b = lg * 4 + r;
    za[((size_t)i * 16 + b) * 64 + w * 16 + lr] = zacc[r] * stats[48 + b];
  }
}

// ---------------------------------------------------------------------------
// P4: z[b,i,d] = attn[b,i,:] @ v[b,:,d] + z_a[i,b,d].
// grid 1024 (b x 16-row i-tile); per-wave-private barrier-free v^T staging,
// dual-stream 4-deep prefetch. attn/v/za reads stay CACHED (L3-reuse).
__global__ __launch_bounds__(256) void k_zv(
    const float* __restrict__ attn, const float* __restrict__ vf,
    const float* __restrict__ za, float* __restrict__ zout)
{
  __shared__ __align__(16) u16 vt[64 * PADJ];
  const int t = threadIdx.x, l = t & 63, w = t >> 6;
  const int b = blockIdx.x & 15, it16 = blockIdx.x >> 4;
  const int lr = l & 15, lg = l >> 4;
  const int i0 = it16 * 16;
  const int jj = l >> 2;
  const int cc = (l & 3) * 4;
  const float* vbase = vf + (size_t)b * 65536 + w * 16 + cc;
  const float* abase = attn + ((size_t)b * 1024 + i0 + lr) * 1024 + lg * 8;
  float zr[4];
#pragma unroll
  for (int r = 0; r < 4; ++r)
    zr[r] = za[((size_t)(i0 + lg * 4 + r) * 16 + b) * 64 + w * 16 + lr];
  fx4 acc = {0.f, 0.f, 0.f, 0.f};
  u16* vtw = vt + (size_t)(w * 16 + cc) * PADJ + jj;
  const u16* vtr = vt + (size_t)(w * 16 + lr) * PADJ + lg * 8;
  auto ldV = [&](int jt, float4& pa, float4& pb) {
    const float* nb = vbase + (size_t)(jt * 32) * 64;
    pa = *(const float4*)(nb + (size_t)jj * 64);
    pb = *(const float4*)(nb + (size_t)(jj + 16) * 64);
  };
  auto ldAt = [&](int jt, float4& t0, float4& t1) {
    const float* p = abase + jt * 32;
    t0 = *(const float4*)(p);
    t1 = *(const float4*)(p + 4);
  };
  auto doT = [&](float4 va, float4 vb, float4 t0, float4 t1) {
    vtw[0 * PADJ]      = (u16)b16(va.x);
    vtw[1 * PADJ]      = (u16)b16(va.y);
    vtw[2 * PADJ]      = (u16)b16(va.z);
    vtw[3 * PADJ]      = (u16)b16(va.w);
    vtw[0 * PADJ + 16] = (u16)b16(vb.x);
    vtw[1 * PADJ + 16] = (u16)b16(vb.y);
    vtw[2 * PADJ + 16] = (u16)b16(vb.z);
    vtw[3 * PADJ + 16] = (u16)b16(vb.w);
    bhalf8 af = pack8(t0, t1);
    bhalf8 bv = *(const bhalf8*)(vtr);
    acc = __builtin_amdgcn_mfma_f32_16x16x32_bf16(af, bv, acc, 0, 0, 0);
  };
  float4 v0a, v0b, v1a, v1b, v2a, v2b, v3a, v3b;
  float4 a0_, a1_, b0_, b1_, c0_, c1_, d0_, d1_;
  ldV(0, v0a, v0b); ldAt(0, a0_, a1_);
  ldV(1, v1a, v1b); ldAt(1, b0_, b1_);
  ldV(2, v2a, v2b); ldAt(2, c0_, c1_);
  ldV(3, v3a, v3b); ldAt(3, d0_, d1_);
#pragma unroll
  for (int jt = 0; jt < 32; jt += 4) {
    doT(v0a, v0b, a0_, a1_); if (jt + 4 < 32) { ldV(jt + 4, v0a, v0b); ldAt(jt + 4, a0_, a1_); }
    doT(v1a, v1b, b0_, b1_); if (jt + 5 < 32) { ldV(jt + 5, v1a, v1b); ldAt(jt + 5, b0_, b1_); }
    doT(v2a, v2b, c0_, c1_); if (jt + 6 < 32) { ldV(jt + 6, v2a, v2b); ldAt(jt + 6, c0_, c1_); }
    doT(v3a, v3b, d0_, d1_); if (jt + 7 < 32) { ldV(jt + 7, v3a, v3b); ldAt(jt + 7, d0_, d1_); }
  }
#pragma unroll
  for (int r = 0; r < 4; ++r)
    zout[((size_t)b * 1024 + i0 + lg * 4 + r) * 64 + w * 16 + lr] = acc[r] + zr[r];
}

// ---------------------------------------------------------------------------
extern "C" void kernel_launch(void* const* d_in, const int* in_sizes, int n_in,
                              void* d_out, int out_size, void* d_ws, size_t ws_size,
                              hipStream_t stream)
{
  const float* x  = (const float*)d_in[0];
  const float* Wq = (const float*)d_in[1];
  const float* Wk = (const float*)d_in[2];
  const float* Wv = (const float*)d_in[3];
  const float* aK = (const float*)d_in[4];
  const float* aV = (const float*)d_in[5];
  float* zout = (float*)d_out;
  float* attn_out = zout + (size_t)16 * 1024 * 64;   // attn after z

  char* ws = (char*)d_ws;                 // layout (44 MB total):
  u16*    qbf = (u16*)(ws);                               //  0.. 2 MB q bf16
  u16*    kbf = (u16*)(ws + (size_t)2  * 1024 * 1024);    //  2.. 4 MB k bf16
  float*  vf  = (float*)(ws + (size_t)4  * 1024 * 1024);  //  4.. 8 MB v fp32
  float*  za  = (float*)(ws + (size_t)8  * 1024 * 1024);  //  8..12 MB z_a [i][b][d]
  __half* qkw = (__half*)(ws + (size_t)12 * 1024 * 1024); // 12..44 MB QK fp16 [i][b][j]

  hipLaunchKernelGGL(k_proj, dim3(256),  dim3(256), 0, stream, x, Wq, Wk, Wv, qbf, kbf, vf);
  hipLaunchKernelGGL(k_qk,   dim3(256),  dim3(256), 0, stream, qbf, kbf, qkw);
  hipLaunchKernelGGL(k_core, dim3(1024), dim3(256), 0, stream, aK, aV, qbf, qkw, attn_out, za);
  hipLaunchKernelGGL(k_zv,   dim3(1024), dim3(256), 0, stream, attn_out, vf, za, zout);
}

// Round 12
// 205.824 us; speedup vs baseline: 6.7980x; 1.0038x over previous
//
#include <hip/hip_runtime.h>
#include <hip/hip_fp16.h>
#include <hip/hip_bf16.h>

// Problem constants: B=16, S=1024, DIN=64, D=64
// out = [ z: 16*1024*64 fp32 | attn: 16*1024*1024 fp32 ]
// R11 structure + qkw intermediate stored as BF16 (was fp16-sized fp32 mix):
// -16 MB write (k_qk), -16 MB read (k_core). Only proven lever = bytes.

typedef unsigned short u16;
typedef __attribute__((ext_vector_type(8))) short bhalf8;   // 8 bf16 (4 VGPRs) - MFMA A/B frag
typedef __attribute__((ext_vector_type(4))) float fx4;      // MFMA C/D frag / NT load vehicle

__device__ __forceinline__ short b16(float f) {             // RNE; pairs fuse to v_cvt_pk_bf16_f32
  __hip_bfloat16 h = __float2bfloat16(f);
  return *reinterpret_cast<short*>(&h);
}
__device__ __forceinline__ float bf2f(short s) {            // exact widen
  union { unsigned u; float f; } v; v.u = ((unsigned)(u16)s) << 16; return v.f;
}

__device__ __forceinline__ bhalf8 pack8(float4 a, float4 b) {
  bhalf8 r;
  r[0] = b16(a.x); r[1] = b16(a.y); r[2] = b16(a.z); r[3] = b16(a.w);
  r[4] = b16(b.x); r[5] = b16(b.y); r[6] = b16(b.z); r[7] = b16(b.w);
  return r;
}

// streaming (no-allocate) float4 load — via ext_vector (builtin requires
// scalar/ext-vector pointee; HIP_vector_type struct is rejected)
__device__ __forceinline__ float4 ldnt(const float* p) {
  fx4 v = __builtin_nontemporal_load((const fx4*)p);
  return make_float4(v[0], v[1], v[2], v[3]);
}

// ---------------------------------------------------------------------------
// P1: q,k,v projections. grid 256, block 256. 64 rows/block, 4 threads/row.
__global__ __launch_bounds__(256) void k_proj(
    const float* __restrict__ x, const float* __restrict__ Wq,
    const float* __restrict__ Wk, const float* __restrict__ Wv,
    u16* __restrict__ qbf, u16* __restrict__ kbf, float* __restrict__ vf)
{
  __shared__ float wl[3 * 4096];
  const int t = threadIdx.x;
  for (int c = t; c < 4096; c += 256) {
    wl[c] = Wq[c]; wl[4096 + c] = Wk[c]; wl[8192 + c] = Wv[c];
  }
  __syncthreads();
  const int row = blockIdx.x * 64 + (t >> 2);
  const int dbase = (t & 3) * 16;
  float xr[64];
  const float4* xp = (const float4*)(x + (size_t)row * 64);
#pragma unroll
  for (int c = 0; c < 16; ++c) {
    float4 v = xp[c];
    xr[4*c] = v.x; xr[4*c+1] = v.y; xr[4*c+2] = v.z; xr[4*c+3] = v.w;
  }
  float aq[16], ak[16], av[16];
#pragma unroll
  for (int m = 0; m < 16; ++m) { aq[m] = 0.f; ak[m] = 0.f; av[m] = 0.f; }
#pragma unroll
  for (int f = 0; f < 64; ++f) {
    const float xv = xr[f];
    const float* wq = wl + f * 64 + dbase;
#pragma unroll
    for (int m = 0; m < 16; ++m) {
      aq[m] = fmaf(xv, wq[m], aq[m]);
      ak[m] = fmaf(xv, wq[4096 + m], ak[m]);
      av[m] = fmaf(xv, wq[8192 + m], av[m]);
    }
  }
  union { u16 u[16]; uint4 q[2]; } pq, pk;
#pragma unroll
  for (int m = 0; m < 16; ++m) { pq.u[m] = (u16)b16(aq[m]); pk.u[m] = (u16)b16(ak[m]); }
  const size_t o = (size_t)row * 64 + dbase;
  *(uint4*)(qbf + o) = pq.q[0]; *(uint4*)(qbf + o + 8) = pq.q[1];
  *(uint4*)(kbf + o) = pk.q[0]; *(uint4*)(kbf + o + 8) = pk.q[1];
  float4* vo = (float4*)(vf + o);
  vo[0] = make_float4(av[0], av[1], av[2], av[3]);
  vo[1] = make_float4(av[4], av[5], av[6], av[7]);
  vo[2] = make_float4(av[8], av[9], av[10], av[11]);
  vo[3] = make_float4(av[12], av[13], av[14], av[15]);
}

// ---------------------------------------------------------------------------
// P2: QK[b,i,j] = q[b,i].k[b,j] (unscaled), stored BF16 layout [i][b][j].
// 4-deep prefetch rotation on the K-tile stream.
__global__ __launch_bounds__(256) void k_qk(
    const u16* __restrict__ qbf, const u16* __restrict__ kbf, u16* __restrict__ qkw)
{
  const int t = threadIdx.x, l = t & 63, w = t >> 6;
  const int bq = blockIdx.x & 15, it = blockIdx.x >> 4;
  const int lr = l & 15, lg = l >> 4;
  const int i0 = it * 64 + w * 16;
  const u16* qp = qbf + (size_t)(bq * 1024 + i0 + lr) * 64 + lg * 8;
  bhalf8 a0 = *(const bhalf8*)(qp);
  bhalf8 a1 = *(const bhalf8*)(qp + 32);
  auto ldK = [&](int jt, bhalf8& b0, bhalf8& b1) {
    const u16* kp = kbf + (size_t)(bq * 1024 + jt * 16 + lr) * 64 + lg * 8;
    b0 = *(const bhalf8*)(kp);
    b1 = *(const bhalf8*)(kp + 32);
  };
  auto doK = [&](int jt, bhalf8 b0, bhalf8 b1) {
    fx4 acc = {0.f, 0.f, 0.f, 0.f};
    acc = __builtin_amdgcn_mfma_f32_16x16x32_bf16(a0, b0, acc, 0, 0, 0);
    acc = __builtin_amdgcn_mfma_f32_16x16x32_bf16(a1, b1, acc, 0, 0, 0);
#pragma unroll
    for (int r = 0; r < 4; ++r) {
      const int i = i0 + lg * 4 + r;
      qkw[((size_t)i * 16 + bq) * 1024 + jt * 16 + lr] = (u16)b16(acc[r]);
    }
  };
  bhalf8 k0a, k0b, k1a, k1b, k2a, k2b, k3a, k3b;
  ldK(0, k0a, k0b); ldK(1, k1a, k1b); ldK(2, k2a, k2b); ldK(3, k3a, k3b);
#pragma unroll
  for (int jt = 0; jt < 64; jt += 4) {
    doK(jt + 0, k0a, k0b); if (jt + 4 < 64) ldK(jt + 4, k0a, k0b);
    doK(jt + 1, k1a, k1b); if (jt + 5 < 64) ldK(jt + 5, k1a, k1b);
    doK(jt + 2, k2a, k2b); if (jt + 6 < 64) ldK(jt + 6, k2a, k2b);
    doK(jt + 3, k3a, k3b); if (jt + 7 < 64) ldK(jt + 7, k3a, k3b);
  }
}

// ---------------------------------------------------------------------------
// P3: per-i core, j in two halves of 512, online softmax merge.
// Phase A 2-deep pipeline (NT aK loads), qkw (bf16) prefetched under A,
// half-0 e in regs (no fixup), phase C 4-deep rotation (NT aV loads).
#define SLD2 516
#define PADJ 40
__global__ __launch_bounds__(256, 4) void k_core(
    const float* __restrict__ aK, const float* __restrict__ aV,
    const u16* __restrict__ qbf, const u16* __restrict__ qkw,
    float* __restrict__ attn_out, float* __restrict__ za)
{
  __shared__ __align__(16) float sl[16 * SLD2];   // 33,024 B
  __shared__ __align__(16) u16 vt[64 * PADJ];     //  5,120 B
  __shared__ float stats[64];  // [0:16) m1, [16:32) s1, [32:48) corr, [48:64) inv
  const int i = blockIdx.x;
  const int t = threadIdx.x, l = t & 63, w = t >> 6;
  const int lr = l & 15, lg = l >> 4;
  const int jj = l >> 2;          // phase-C: tile-local j
  const int cc = (l & 3) * 4;     // phase-C: d-chunk within wave's 16

  // A-frags: Q rows b=lr at position i  (A[m=b][k=d])
  const u16* qp = qbf + (size_t)(lr * 1024 + i) * 64 + lg * 8;
  bhalf8 a0 = *(const bhalf8*)(qp);
  bhalf8 a1 = *(const bhalf8*)(qp + 32);

  fx4 zacc = {0.f, 0.f, 0.f, 0.f};   // D[m=b][n=d_local]: b=lg*4+r, d=w*16+lr
  bhalf8 e1b[4];                     // half-0 raw e (rows w*4+rr, j=l*8..+7)

#pragma unroll
  for (int h = 0; h < 2; ++h) {
    // ---- prefetch qkw rows for phase B (bf16, 16 B/lane; in flight across A)
    uint4 qv[4];
#pragma unroll
    for (int rr = 0; rr < 4; ++rr)
      qv[rr] = *(const uint4*)(qkw + ((size_t)i * 16 + w * 4 + rr) * 1024 + h * 512 + l * 8);

    // ---- phase A: sl = Q_i @ aK_half^T, 8 tiles, 2-deep pipeline, NT loads
    const float* base = aK + ((size_t)i * 1024 + h * 512 + lr) * 64 + lg * 8;
    auto ldA = [&](int tt, float4* c) {
      const float* p = base + (size_t)((w + tt * 4) * 16) * 64;
      c[0] = ldnt(p);
      c[1] = ldnt(p + 4);
      c[2] = ldnt(p + 32);
      c[3] = ldnt(p + 36);
    };
    auto doA = [&](int tt, const float4* c) {
      fx4 acc = {0.f, 0.f, 0.f, 0.f};
      acc = __builtin_amdgcn_mfma_f32_16x16x32_bf16(a0, pack8(c[0], c[1]), acc, 0, 0, 0);
      acc = __builtin_amdgcn_mfma_f32_16x16x32_bf16(a1, pack8(c[2], c[3]), acc, 0, 0, 0);
      const int j0 = (w + tt * 4) * 16;
#pragma unroll
      for (int r = 0; r < 4; ++r)          // C: col=lane&15 (j), row=(lane>>4)*4+r (b)
        sl[(lg * 4 + r) * SLD2 + j0 + lr] = acc[r];
    };
    float4 cA[4], cB[4];
    ldA(0, cA); ldA(1, cB);
#pragma unroll
    for (int tt = 0; tt < 8; tt += 2) {
      doA(tt, cA);     if (tt + 2 < 8) ldA(tt + 2, cA);
      doA(tt + 1, cB); if (tt + 3 < 8) ldA(tt + 3, cB);
    }
    __syncthreads();

    // ---- phase B: softmax rows w*4..w*4+3; lane covers j = l*8..l*8+7
    if (h == 0) {
#pragma unroll
      for (int rr = 0; rr < 4; ++rr) {
        const int row = w * 4 + rr;
        float* rp = sl + row * SLD2;
        const u16* qq = (const u16*)&qv[rr];
        float4 x0 = *(const float4*)(rp + l * 8);
        float4 x1 = *(const float4*)(rp + l * 8 + 4);
        float v8[8] = {x0.x + bf2f(qq[0]), x0.y + bf2f(qq[1]),
                       x0.z + bf2f(qq[2]), x0.w + bf2f(qq[3]),
                       x1.x + bf2f(qq[4]), x1.y + bf2f(qq[5]),
                       x1.z + bf2f(qq[6]), x1.w + bf2f(qq[7])};
        float mx = -3.0e30f;
#pragma unroll
        for (int c = 0; c < 8; ++c) mx = fmaxf(mx, v8[c]);
#pragma unroll
        for (int off = 32; off; off >>= 1) mx = fmaxf(mx, __shfl_xor(mx, off));
        float e8[8]; float sum = 0.f;
#pragma unroll
        for (int c = 0; c < 8; ++c) { e8[c] = __expf((v8[c] - mx) * 0.125f); sum += e8[c]; }
        bhalf8 eb;
#pragma unroll
        for (int c = 0; c < 8; ++c) eb[c] = b16(e8[c]);
        *(bhalf8*)((u16*)rp + l * 8) = eb;                  // e-bf16 row head (PV A-frag)
        e1b[rr] = eb;                                       // keep for final attn write
#pragma unroll
        for (int off = 32; off; off >>= 1) sum += __shfl_xor(sum, off);
        if (l == 0) { stats[row] = mx; stats[16 + row] = sum; }
      }
    } else {
#pragma unroll
      for (int rr = 0; rr < 4; ++rr) {
        const int row = w * 4 + rr;
        float* rp = sl + row * SLD2;
        const u16* qq = (const u16*)&qv[rr];
        float4 x0 = *(const float4*)(rp + l * 8);
        float4 x1 = *(const float4*)(rp + l * 8 + 4);
        float v8[8] = {x0.x + bf2f(qq[0]), x0.y + bf2f(qq[1]),
                       x0.z + bf2f(qq[2]), x0.w + bf2f(qq[3]),
                       x1.x + bf2f(qq[4]), x1.y + bf2f(qq[5]),
                       x1.z + bf2f(qq[6]), x1.w + bf2f(qq[7])};
        float mx = -3.0e30f;
#pragma unroll
        for (int c = 0; c < 8; ++c) mx = fmaxf(mx, v8[c]);
#pragma unroll
        for (int off = 32; off; off >>= 1) mx = fmaxf(mx, __shfl_xor(mx, off));
        const float m1 = stats[row];
        const float m  = fmaxf(m1, mx);
        const float corr = __expf((m1 - m) * 0.125f);
        float e8[8]; float sum = 0.f;
#pragma unroll
        for (int c = 0; c < 8; ++c) { e8[c] = __expf((v8[c] - m) * 0.125f); sum += e8[c]; }
        bhalf8 eb;
#pragma unroll
        for (int c = 0; c < 8; ++c) eb[c] = b16(e8[c]);
        *(bhalf8*)((u16*)rp + l * 8) = eb;                  // raw e2 for PV
#pragma unroll
        for (int off = 32; off; off >>= 1) sum += __shfl_xor(sum, off);
        const float inv = 1.0f / (stats[16 + row] * corr + sum);
        // final attn half-1
        float* ao1 = attn_out + ((size_t)row * 1024 + i) * 1024 + 512;
        *(float4*)(ao1 + l * 8)     = make_float4(e8[0]*inv, e8[1]*inv, e8[2]*inv, e8[3]*inv);
        *(float4*)(ao1 + l * 8 + 4) = make_float4(e8[4]*inv, e8[5]*inv, e8[6]*inv, e8[7]*inv);
        // final attn half-0 from register-held bf16 e1 (no re-read, no fixup)
        const float f = corr * inv;
        float* ao0 = attn_out + ((size_t)row * 1024 + i) * 1024;
        *(float4*)(ao0 + l * 8)     = make_float4(bf2f(e1b[rr][0])*f, bf2f(e1b[rr][1])*f,
                                                  bf2f(e1b[rr][2])*f, bf2f(e1b[rr][3])*f);
        *(float4*)(ao0 + l * 8 + 4) = make_float4(bf2f(e1b[rr][4])*f, bf2f(e1b[rr][5])*f,
                                                  bf2f(e1b[rr][6])*f, bf2f(e1b[rr][7])*f);
        if (l == 0) { stats[32 + row] = corr; stats[48 + row] = inv; }
      }
    }
    __syncthreads();

    // ---- phase C: PV (barrier-free, per-wave-private vt), 4-deep rotation,
    // NT aV loads (read-once stream).
    if (h == 1) {
#pragma unroll
      for (int r = 0; r < 4; ++r) zacc[r] *= stats[32 + lg * 4 + r];   // corr
    }
    const float* avbase = aV + ((size_t)i * 1024 + h * 512) * 64 + w * 16 + cc;
    u16* vtw = vt + (size_t)(w * 16 + cc) * PADJ + jj;
    const u16* vtr = vt + (size_t)(w * 16 + lr) * PADJ + lg * 8;
    const u16* slr = (const u16*)(sl + (size_t)lr * SLD2);
    auto ldC = [&](int it, float4& pa, float4& pb) {
      const float* nb = avbase + (size_t)(it * 32) * 64;
      pa = ldnt(nb + (size_t)jj * 64);
      pb = ldnt(nb + (size_t)(jj + 16) * 64);
    };
    auto doC = [&](int it, float4 ca, float4 cb) {
      vtw[0 * PADJ]      = (u16)b16(ca.x);
      vtw[1 * PADJ]      = (u16)b16(ca.y);
      vtw[2 * PADJ]      = (u16)b16(ca.z);
      vtw[3 * PADJ]      = (u16)b16(ca.w);
      vtw[0 * PADJ + 16] = (u16)b16(cb.x);
      vtw[1 * PADJ + 16] = (u16)b16(cb.y);
      vtw[2 * PADJ + 16] = (u16)b16(cb.z);
      vtw[3 * PADJ + 16] = (u16)b16(cb.w);
      // within-wave LDS write->read (in-order DS pipe; compiler orders may-alias)
      bhalf8 ea = *(const bhalf8*)(slr + it * 32 + lg * 8);
      bhalf8 bv = *(const bhalf8*)(vtr);
      zacc = __builtin_amdgcn_mfma_f32_16x16x32_bf16(ea, bv, zacc, 0, 0, 0);
    };
    float4 p0a, p0b, p1a, p1b, p2a, p2b, p3a, p3b;
    ldC(0, p0a, p0b); ldC(1, p1a, p1b); ldC(2, p2a, p2b); ldC(3, p3a, p3b);
#pragma unroll
    for (int it = 0; it < 16; it += 4) {
      doC(it + 0, p0a, p0b); if (it + 4 < 16) ldC(it + 4, p0a, p0b);
      doC(it + 1, p1a, p1b); if (it + 5 < 16) ldC(it + 5, p1a, p1b);
      doC(it + 2, p2a, p2b); if (it + 6 < 16) ldC(it + 6, p2a, p2b);
      doC(it + 3, p3a, p3b); if (it + 7 < 16) ldC(it + 7, p3a, p3b);
    }
    __syncthreads();   // protect sl/vt until all waves' PV done
  }

  // ---- za directly from accumulator: b = lg*4+r, d = w*16+lr
#pragma unroll
  for (int r = 0; r < 4; ++r) {
    const int b = lg * 4 + r;
    za[((size_t)i * 16 + b) * 64 + w * 16 + lr] = zacc[r] * stats[48 + b];
  }
}

// ---------------------------------------------------------------------------
// P4: z[b,i,d] = attn[b,i,:] @ v[b,:,d] + z_a[i,b,d].
// grid 1024 (b x 16-row i-tile); per-wave-private barrier-free v^T staging,
// dual-stream 4-deep prefetch. attn/v/za reads stay CACHED (L3-reuse).
__global__ __launch_bounds__(256) void k_zv(
    const float* __restrict__ attn, const float* __restrict__ vf,
    const float* __restrict__ za, float* __restrict__ zout)
{
  __shared__ __align__(16) u16 vt[64 * PADJ];
  const int t = threadIdx.x, l = t & 63, w = t >> 6;
  const int b = blockIdx.x & 15, it16 = blockIdx.x >> 4;
  const int lr = l & 15, lg = l >> 4;
  const int i0 = it16 * 16;
  const int jj = l >> 2;
  const int cc = (l & 3) * 4;
  const float* vbase = vf + (size_t)b * 65536 + w * 16 + cc;
  const float* abase = attn + ((size_t)b * 1024 + i0 + lr) * 1024 + lg * 8;
  float zr[4];
#pragma unroll
  for (int r = 0; r < 4; ++r)
    zr[r] = za[((size_t)(i0 + lg * 4 + r) * 16 + b) * 64 + w * 16 + lr];
  fx4 acc = {0.f, 0.f, 0.f, 0.f};
  u16* vtw = vt + (size_t)(w * 16 + cc) * PADJ + jj;
  const u16* vtr = vt + (size_t)(w * 16 + lr) * PADJ + lg * 8;
  auto ldV = [&](int jt, float4& pa, float4& pb) {
    const float* nb = vbase + (size_t)(jt * 32) * 64;
    pa = *(const float4*)(nb + (size_t)jj * 64);
    pb = *(const float4*)(nb + (size_t)(jj + 16) * 64);
  };
  auto ldAt = [&](int jt, float4& t0, float4& t1) {
    const float* p = abase + jt * 32;
    t0 = *(const float4*)(p);
    t1 = *(const float4*)(p + 4);
  };
  auto doT = [&](float4 va, float4 vb, float4 t0, float4 t1) {
    vtw[0 * PADJ]      = (u16)b16(va.x);
    vtw[1 * PADJ]      = (u16)b16(va.y);
    vtw[2 * PADJ]      = (u16)b16(va.z);
    vtw[3 * PADJ]      = (u16)b16(va.w);
    vtw[0 * PADJ + 16] = (u16)b16(vb.x);
    vtw[1 * PADJ + 16] = (u16)b16(vb.y);
    vtw[2 * PADJ + 16] = (u16)b16(vb.z);
    vtw[3 * PADJ + 16] = (u16)b16(vb.w);
    bhalf8 af = pack8(t0, t1);
    bhalf8 bv = *(const bhalf8*)(vtr);
    acc = __builtin_amdgcn_mfma_f32_16x16x32_bf16(af, bv, acc, 0, 0, 0);
  };
  float4 v0a, v0b, v1a, v1b, v2a, v2b, v3a, v3b;
  float4 a0_, a1_, b0_, b1_, c0_, c1_, d0_, d1_;
  ldV(0, v0a, v0b); ldAt(0, a0_, a1_);
  ldV(1, v1a, v1b); ldAt(1, b0_, b1_);
  ldV(2, v2a, v2b); ldAt(2, c0_, c1_);
  ldV(3, v3a, v3b); ldAt(3, d0_, d1_);
#pragma unroll
  for (int jt = 0; jt < 32; jt += 4) {
    doT(v0a, v0b, a0_, a1_); if (jt + 4 < 32) { ldV(jt + 4, v0a, v0b); ldAt(jt + 4, a0_, a1_); }
    doT(v1a, v1b, b0_, b1_); if (jt + 5 < 32) { ldV(jt + 5, v1a, v1b); ldAt(jt + 5, b0_, b1_); }
    doT(v2a, v2b, c0_, c1_); if (jt + 6 < 32) { ldV(jt + 6, v2a, v2b); ldAt(jt + 6, c0_, c1_); }
    doT(v3a, v3b, d0_, d1_); if (jt + 7 < 32) { ldV(jt + 7, v3a, v3b); ldAt(jt + 7, d0_, d1_); }
  }
#pragma unroll
  for (int r = 0; r < 4; ++r)
    zout[((size_t)b * 1024 + i0 + lg * 4 + r) * 64 + w * 16 + lr] = acc[r] + zr[r];
}

// ---------------------------------------------------------------------------
extern "C" void kernel_launch(void* const* d_in, const int* in_sizes, int n_in,
                              void* d_out, int out_size, void* d_ws, size_t ws_size,
                              hipStream_t stream)
{
  const float* x  = (const float*)d_in[0];
  const float* Wq = (const float*)d_in[1];
  const float* Wk = (const float*)d_in[2];
  const float* Wv = (const float*)d_in[3];
  const float* aK = (const float*)d_in[4];
  const float* aV = (const float*)d_in[5];
  float* zout = (float*)d_out;
  float* attn_out = zout + (size_t)16 * 1024 * 64;   // attn after z

  char* ws = (char*)d_ws;                 // layout (28 MB used):
  u16*    qbf = (u16*)(ws);                               //  0.. 2 MB q bf16
  u16*    kbf = (u16*)(ws + (size_t)2  * 1024 * 1024);    //  2.. 4 MB k bf16
  float*  vf  = (float*)(ws + (size_t)4  * 1024 * 1024);  //  4.. 8 MB v fp32
  float*  za  = (float*)(ws + (size_t)8  * 1024 * 1024);  //  8..12 MB z_a [i][b][d]
  u16*    qkw = (u16*)(ws + (size_t)12 * 1024 * 1024);    // 12..28 MB QK bf16 [i][b][j]

  hipLaunchKernelGGL(k_proj, dim3(256),  dim3(256), 0, stream, x, Wq, Wk, Wv, qbf, kbf, vf);
  hipLaunchKernelGGL(k_qk,   dim3(256),  dim3(256), 0, stream, qbf, kbf, qkw);
  hipLaunchKernelGGL(k_core, dim3(1024), dim3(256), 0, stream, aK, aV, qbf, qkw, attn_out, za);
  hipLaunchKernelGGL(k_zv,   dim3(1024), dim3(256), 0, stream, attn_out, vf, za, zout);
}